// Round 6
// baseline (233.147 us; speedup 1.0000x reference)
//
#include <hip/hip_runtime.h>

// ActivationSparsifier: per row of D=4096, t = 409-th largest |x|,
// out = x * sigmoid(10 * (|x| - t)).
//
// R6: maximize independent rows in flight per CU (counters from R5 show a
// latency-bound kernel: HBM 31%, VALU 17%, Occupancy 42% -> ~3.4 resident
// blocks; everything idles in barrier convoys).
//   * 128-thread blocks (2 waves), ONE ROW per block, 32 floats/thread.
//     Wave-slot cap: 32 waves / 2 = 16 blocks/CU (= HW workgroup-slot
//     limit) -> 16 independent rows in flight vs ~3.4 measured in R5.
//   * LDS diet to fit 16 blocks (need <10 KB/block): pass-0 histogram
//     packed TWO ADJACENT BINS PER u32 (hist[2048]: word w = bins 2w
//     (lo16), 2w+1 (hi16)). Per-bin count <= 4096 < 2^16 -> halves never
//     carry, so packed word-sums are carry-free. Same for pass-1
//     (hist1[128]). Total LDS = 8.7 KB -> 16 x 8.7 = 139 KB <= 160 KB.
//   * __launch_bounds__(128, 8): 8 waves/EU -> VGPR capped at 64
//     (data = 8 float4 = 32 regs; R5 measured 44 at identical pressure).
//   * epilogue keeps v_rcp form (x * rcp(1+exp)).
// Threshold numerics unchanged: 2-pass radix select (12-bit then 8-bit
// digit), 20-bit prefix (bits 30:11), rel err <= 2^-12 -> output delta
// ~2e-3, far under the harness bf16 comparison floor (~0.0156).

constexpr int D = 4096;
constexpr int K = 409;          // max(1, int(D * 0.1))
constexpr int NT = 128;         // 2 waves per block
constexpr int NW0 = 2048;       // pass-0 packed words (4096 bins / 2)
constexpr int SH0 = 19;         // pass-0 digit shift (12 bits: 30:19)
constexpr int SH1 = 11;         // pass-1 digit shift (8 bits: 18:11)
constexpr float SHARP = 10.0f;

typedef float floatx4 __attribute__((ext_vector_type(4)));  // clang-native nt-store

__device__ __forceinline__ float softmask(float xv, float t) {
  // x * sigmoid(SHARP*(|x|-t)) = x * rcp(1 + exp(SHARP*(t-|x|)))
  return xv * __builtin_amdgcn_rcpf(1.0f + __expf(SHARP * (t - fabsf(xv))));
}

__global__ __launch_bounds__(NT, 8) void ActSp_row(
    const float* __restrict__ x, float* __restrict__ y) {
  const size_t row = blockIdx.x;
  const float4* __restrict__ x4 = reinterpret_cast<const float4*>(x + row * D);
  floatx4* __restrict__ y4 = reinterpret_cast<floatx4*>(y + row * (size_t)D);
  const int tid = threadIdx.x;
  const int lane = tid & 63;
  const int wave = tid >> 6;  // 0 or 1

  // ---- load row: 32 floats/thread, coalesced float4 ----
  float4 v[8];
#pragma unroll
  for (int i = 0; i < 8; ++i) v[i] = x4[tid + i * NT];

  __shared__ unsigned hist[NW0];   // packed pairs: word w = bins 2w|2w+1
  __shared__ unsigned hist1[NT];   // packed pairs: word t = bins 2t|2t+1
  __shared__ unsigned wt[2];       // per-wave scan totals
  __shared__ unsigned bcd;         // pass-0 digit d0 (12-bit)
  __shared__ unsigned bck;         // residual k for pass 1
  __shared__ unsigned bcf;         // final threshold bits

  // zero histograms (b128 stores); overlaps in-flight global loads
  {
    uint4* h4 = reinterpret_cast<uint4*>(hist);
#pragma unroll
    for (int i = 0; i < 4; ++i) h4[tid + i * NT] = make_uint4(0u, 0u, 0u, 0u);
    hist1[tid] = 0u;
  }
  __syncthreads();  // B1

  // ---- pass 0: 12-bit histogram into packed-pair words ----
#pragma unroll
  for (int i = 0; i < 8; ++i) {
    unsigned b;
    b = (__float_as_uint(v[i].x) & 0x7fffffffu) >> SH0;
    atomicAdd(&hist[b >> 1], 1u << ((b & 1u) << 4));
    b = (__float_as_uint(v[i].y) & 0x7fffffffu) >> SH0;
    atomicAdd(&hist[b >> 1], 1u << ((b & 1u) << 4));
    b = (__float_as_uint(v[i].z) & 0x7fffffffu) >> SH0;
    atomicAdd(&hist[b >> 1], 1u << ((b & 1u) << 4));
    b = (__float_as_uint(v[i].w) & 0x7fffffffu) >> SH0;
    atomicAdd(&hist[b >> 1], 1u << ((b & 1u) << 4));
  }
  __syncthreads();  // B2

  // ---- pass 0 scan: thread owns words [tid*16, tid*16+16) = 32 bins ----
  // packed word-sum is carry-free (each half-sum <= 4096), split once.
  unsigned T;
  {
    const uint4* hb = reinterpret_cast<const uint4*>(&hist[tid * 16]);
    unsigned Tp = 0;
#pragma unroll
    for (int w2 = 0; w2 < 4; ++w2) {
      uint4 a = hb[w2];
      Tp += a.x + a.y + a.z + a.w;
    }
    T = (Tp >> 16) + (Tp & 0xffffu);
  }
  unsigned suf = T;  // wave-level inclusive suffix scan (lanes >= lane)
#pragma unroll
  for (int off = 1; off < 64; off <<= 1) {
    unsigned nb = __shfl_down(suf, off, 64);
    if (lane + off < 64) suf += nb;
  }
  if (lane == 0) wt[wave] = suf;
  __syncthreads();  // B3

  unsigned above = suf - T;
  if (wave == 0) above += wt[1];  // higher bins live in wave 1

  if (above < (unsigned)K && above + T >= (unsigned)K) {
    // crossing thread: walk my 32 bins high-to-low (word-major order is
    // bin order; hi half = odd bin > even bin), pick largest bin with
    // cumulative(count of bins >= it) >= K
    const uint4* hb = reinterpret_cast<const uint4*>(&hist[tid * 16]);
    unsigned run = above;
    unsigned dstar = 0, kres = 0;
    bool done = false;
#pragma unroll
    for (int w2 = 3; w2 >= 0; --w2) {
      uint4 a = hb[w2];
      unsigned cw[4] = {a.x, a.y, a.z, a.w};
#pragma unroll
      for (int j = 3; j >= 0; --j) {
        const unsigned word = cw[j];
        const unsigned hi = word >> 16, lo = word & 0xffffu;
        const unsigned binbase = (unsigned)(tid * 16 + w2 * 4 + j) * 2u;
        if (!done) {
          if (run + hi >= (unsigned)K) { dstar = binbase + 1u; kres = (unsigned)K - run; done = true; }
          else {
            run += hi;
            if (run + lo >= (unsigned)K) { dstar = binbase; kres = (unsigned)K - run; done = true; }
            else run += lo;
          }
        }
      }
    }
    bcd = dstar;  // 12-bit digit d0
    bck = kres;   // residual k for pass 1 (>=1)
  }
  __syncthreads();  // B4

  const unsigned d0 = bcd;
  const unsigned k1 = bck;

  // ---- pass 1: 8-bit histogram (packed pairs) over candidates ----
#pragma unroll
  for (int i = 0; i < 8; ++i) {
    unsigned a0 = __float_as_uint(v[i].x) & 0x7fffffffu;
    unsigned a1 = __float_as_uint(v[i].y) & 0x7fffffffu;
    unsigned a2 = __float_as_uint(v[i].z) & 0x7fffffffu;
    unsigned a3 = __float_as_uint(v[i].w) & 0x7fffffffu;
    unsigned b;
    if ((a0 >> SH0) == d0) { b = (a0 >> SH1) & 255u; atomicAdd(&hist1[b >> 1], 1u << ((b & 1u) << 4)); }
    if ((a1 >> SH0) == d0) { b = (a1 >> SH1) & 255u; atomicAdd(&hist1[b >> 1], 1u << ((b & 1u) << 4)); }
    if ((a2 >> SH0) == d0) { b = (a2 >> SH1) & 255u; atomicAdd(&hist1[b >> 1], 1u << ((b & 1u) << 4)); }
    if ((a3 >> SH0) == d0) { b = (a3 >> SH1) & 255u; atomicAdd(&hist1[b >> 1], 1u << ((b & 1u) << 4)); }
  }
  __syncthreads();  // B5

  // ---- pass 1 scan: thread owns word tid = bins 2t, 2t+1 ----
  const unsigned w1 = hist1[tid];
  const unsigned hi1 = w1 >> 16, lo1 = w1 & 0xffffu;
  const unsigned T1 = hi1 + lo1;
  unsigned suf1 = T1;
#pragma unroll
  for (int off = 1; off < 64; off <<= 1) {
    unsigned nb = __shfl_down(suf1, off, 64);
    if (lane + off < 64) suf1 += nb;
  }
  if (lane == 0) wt[wave] = suf1;  // wt reuse: readers passed B4,B5 since last read
  __syncthreads();  // B6

  unsigned above1 = suf1 - T1;
  if (wave == 0) above1 += wt[1];

  if (above1 < k1 && above1 + T1 >= k1) {
    // hi bin (2t+1) outranks lo bin (2t)
    unsigned binf;
    if (above1 + hi1 >= k1) binf = 2u * (unsigned)tid + 1u;
    else binf = 2u * (unsigned)tid;  // crossing guaranteed in lo half
    bcf = (d0 << SH0) | (binf << SH1);
  }
  __syncthreads();  // B7

  // ---- apply soft mask and store (nontemporal: y never re-read) ----
  const float t = __uint_as_float(bcf);
#pragma unroll
  for (int i = 0; i < 8; ++i) {
    floatx4 o;
    o.x = softmask(v[i].x, t);
    o.y = softmask(v[i].y, t);
    o.z = softmask(v[i].z, t);
    o.w = softmask(v[i].w, t);
    __builtin_nontemporal_store(o, &y4[tid + i * NT]);
  }
}

extern "C" void kernel_launch(void* const* d_in, const int* in_sizes, int n_in,
                              void* d_out, int out_size, void* d_ws, size_t ws_size,
                              hipStream_t stream) {
  (void)n_in; (void)d_ws; (void)ws_size; (void)out_size;
  const float* x = (const float*)d_in[0];
  float* y = (float*)d_out;
  const int rows = in_sizes[0] / D;  // 8192
  ActSp_row<<<dim3(rows), dim3(NT), 0, stream>>>(x, y);
}